// Round 14
// baseline (142.507 us; speedup 1.0000x reference)
//
#include <hip/hip_runtime.h>
#include <hip/hip_bf16.h>
#include <cstdint>
#include <cstddef>

typedef unsigned short u16;
typedef __attribute__((ext_vector_type(8))) short bf16x8;
typedef __attribute__((ext_vector_type(4))) float f32x4;

#define MFMA16(a, b, c) __builtin_amdgcn_mfma_f32_16x16x32_bf16((a), (b), (c), 0, 0, 0)

// ---------- helpers ----------
__device__ __forceinline__ u16 bf16u(float f) {
  union { float f; unsigned u; } x; x.f = f;
  unsigned lsb = (x.u >> 16) & 1u;
  return (u16)((x.u + 0x7fffu + lsb) >> 16);   // RNE
}

__device__ __forceinline__ unsigned cvt_pk_bf16(float lo, float hi) {
  unsigned r;
  asm("v_cvt_pk_bf16_f32 %0, %1, %2" : "=v"(r) : "v"(lo), "v"(hi));
  return r;
}

// DPP rotate within 16-lane rows (VALU cross-lane reduce)
template <int N>
__device__ __forceinline__ float dpp_ror(float v) {
  int r = __builtin_amdgcn_update_dpp(0, __builtin_bit_cast(int, v),
                                      0x120 | N, 0xF, 0xF, false);
  return __builtin_bit_cast(float, r);
}
__device__ __forceinline__ float rowmax16(float v) {
  v = fmaxf(v, dpp_ror<1>(v));
  v = fmaxf(v, dpp_ror<2>(v));
  v = fmaxf(v, dpp_ror<4>(v));
  v = fmaxf(v, dpp_ror<8>(v));
  return v;
}
__device__ __forceinline__ float rowsum16(float v) {
  v += dpp_ror<1>(v);
  v += dpp_ror<2>(v);
  v += dpp_ror<4>(v);
  v += dpp_ror<8>(v);
  return v;
}

__device__ __forceinline__ void gload16(const void* g, void* l) {
  __builtin_amdgcn_global_load_lds(
      (const __attribute__((address_space(1))) unsigned int*)g,
      (__attribute__((address_space(3))) unsigned int*)l, 16, 0, 0);
}

// XOR-swizzled element offset for [rows][64] bf16 LDS tiles (128B rows, 8x16B units).
__device__ __forceinline__ int swz128(int row, int u) {
  return row * 64 + ((u ^ (row & 7)) << 3);
}

// ---------- fp32 -> bf16 convert (all 7 tensors, one launch, exact 1-D grid) ----------
// blocks 0..12287: q/k/v (4096 each); 12288..16383: Wq/Wk/Wv/Wo (1024 each)
__global__ __launch_bounds__(256) void cvt_all(
    const float* __restrict__ q, const float* __restrict__ k, const float* __restrict__ v,
    const float* __restrict__ wq, const float* __restrict__ wk,
    const float* __restrict__ wv, const float* __restrict__ wo,
    u16* __restrict__ xq, u16* __restrict__ xk, u16* __restrict__ xv,
    u16* __restrict__ wqb, u16* __restrict__ wkb, u16* __restrict__ wvb,
    u16* __restrict__ wob) {
  const int bid = blockIdx.x;
  const float* s;
  u16* d;
  int local;
  if (bid < 12288) {
    const int z = bid >> 12;          // 0..2
    local = bid & 4095;
    s = (z == 0) ? q : (z == 1 ? k : v);
    d = (z == 0) ? xq : (z == 1 ? xk : xv);
  } else {
    const int z = (bid - 12288) >> 10;   // 0..3
    local = (bid - 12288) & 1023;
    s = (z == 0) ? wq : (z == 1 ? wk : (z == 2 ? wv : wo));
    d = (z == 0) ? wqb : (z == 1 ? wkb : (z == 2 ? wvb : wob));
  }
  const int i = (local * 256 + threadIdx.x) * 4;
  float4 f = *(const float4*)(s + i);
  ushort4 o = make_ushort4(bf16u(f.x), bf16u(f.y), bf16u(f.z), bf16u(f.w));
  *(ushort4*)(d + i) = o;
}

// ---------- GEMM: C = A(bf16,[4096x1024]) * W^T(bf16,[1024x1024] row-major [N,K]) + bias ----------
// MODE 0 (QKV): 64x128 tile, 1536 blocks = 6 blocks/CU (verified r11).
// MODE 1 (out-proj): 32x128 tile, 1024 blocks = 4 blocks/CU (was 2 — grid-
// starved). Per-output MFMA chain identical -> bitwise-same results.
template <int MODE>
__global__ __launch_bounds__(256) void mha_gemm(
    const u16* __restrict__ A0, const u16* __restrict__ A1, const u16* __restrict__ A2,
    const u16* __restrict__ W0, const u16* __restrict__ W1, const u16* __restrict__ W2,
    const float* __restrict__ b0, const float* __restrict__ b1, const float* __restrict__ b2,
    u16* __restrict__ o0, u16* __restrict__ o1, u16* __restrict__ o2,
    float* __restrict__ of) {
  constexpr int BM = (MODE == 0) ? 64 : 32;   // M-tile
  constexpr int MR = BM / 32;                 // A fragments per wave (2 or 1)
  const int tid = threadIdx.x;
  const int lane = tid & 63;
  const int wid = tid >> 6;
  const int wr = wid >> 1, wc = wid & 1;   // wave tile: rows wr*(MR*16), cols wc*64
  const int bm = blockIdx.x, bn = blockIdx.y;
  const int z = (MODE == 0) ? blockIdx.z : 0;

  const u16* Ap = (z == 0) ? A0 : (z == 1 ? A1 : A2);
  const u16* Wp = (z == 0) ? W0 : (z == 1 ? W1 : W2);
  const float* bias = (z == 0) ? b0 : (z == 1 ? b1 : b2);
  u16* ob = (z == 0) ? o0 : (z == 1 ? o1 : o2);

  __shared__ __align__(16) u16 Als[BM * 64];
  __shared__ __align__(16) u16 Bls[128 * 64];   // 16 KB

  const u16* Abase = Ap + (size_t)bm * BM * 1024;
  const u16* Wbase = Wp + (size_t)bn * 128 * 1024;

  // loop-invariant LDS read offsets
  int aoff[2][MR], boff[2][4];
#pragma unroll
  for (int ks = 0; ks < 2; ++ks) {
#pragma unroll
    for (int m = 0; m < MR; ++m)
      aoff[ks][m] = swz128(wr * (MR * 16) + m * 16 + (lane & 15), ks * 4 + (lane >> 4));
#pragma unroll
    for (int n = 0; n < 4; ++n)
      boff[ks][n] = swz128(wc * 64 + n * 16 + (lane & 15), ks * 4 + (lane >> 4));
  }

  // loop-invariant staging pointers / LDS destinations
  const u16* aptr[MR];   // A: BM rows -> BM*8 units -> MR/thread
  const u16* wptr[4];    // B: 128 rows -> 1024 units -> 4/thread
  int lda[MR], ldb[4];
#pragma unroll
  for (int i = 0; i < 4; ++i) {
    const int L = i * 256 + tid;
    const int r = L >> 3;
    const int c8 = (L & 7) ^ (r & 7);
    if (i < MR) {
      aptr[i] = Abase + (size_t)r * 1024 + c8 * 8;   // + kt*64 per tile
      lda[i] = L * 8;
    }
    wptr[i] = Wbase + (size_t)r * 1024 + c8 * 8;
    ldb[i] = L * 8;
  }

  f32x4 acc[MR][4] = {};

  for (int kt = 0; kt < 16; ++kt) {
    const int k0 = kt * 64;
    __syncthreads();
#pragma unroll
    for (int i = 0; i < MR; ++i) gload16(aptr[i] + k0, &Als[lda[i]]);
#pragma unroll
    for (int i = 0; i < 4; ++i) gload16(wptr[i] + k0, &Bls[ldb[i]]);
    __syncthreads();
#pragma unroll
    for (int ks = 0; ks < 2; ++ks) {
      bf16x8 af[MR], bw[4];
#pragma unroll
      for (int m = 0; m < MR; ++m) af[m] = *(const bf16x8*)&Als[aoff[ks][m]];
#pragma unroll
      for (int n = 0; n < 4; ++n) bw[n] = *(const bf16x8*)&Bls[boff[ks][n]];
#pragma unroll
      for (int m = 0; m < MR; ++m)
#pragma unroll
        for (int n = 0; n < 4; ++n)
          acc[m][n] = MFMA16(af[m], bw[n], acc[m][n]);
    }
  }

  // Q gets 1/sqrt(64) * log2(e) so attention scores are in exp2 domain
  const float scl = (MODE == 0 && z == 0) ? 0.125f * 1.4426950408889634f : 1.0f;
#pragma unroll
  for (int n = 0; n < 4; ++n) {
    const int col = bn * 128 + wc * 64 + n * 16 + (lane & 15);
    const float bb = bias[col];
#pragma unroll
    for (int m = 0; m < MR; ++m) {
#pragma unroll
      for (int r = 0; r < 4; ++r) {
        const int row = bm * BM + wr * (MR * 16) + m * 16 + ((lane >> 4) << 2) + r;
        float val = acc[m][n][r] + bb;
        if (MODE == 0) {
          val *= scl;
          const int bi = row >> 11, ss = row & 2047;
          const int hh = col >> 6, dd = col & 63;
          size_t off;
          if (z == 2) off = (((size_t)(bi * 16 + hh)) * 64 + dd) * 2048 + ss;   // V^T
          else        off = (((size_t)(bi * 16 + hh)) * 2048 + ss) * 64 + dd;   // Q,K
          ob[off] = bf16u(val);
        } else {
          of[(size_t)row * 1024 + col] = val;
        }
      }
    }
  }
}

// ---------- flash attention (BYTE-IDENTICAL to r6/r10/r11/r13 — verified passing) ----------
// Q,K: [B,NH,S,64] bf16 (Q pre-scaled by 0.125*log2e => scores in log2 units).
// V: [B,NH,64,S] bf16 (transposed). Out: [B,S,H] bf16.
// Per-row running max + defer-max THR=8 + deferred denominator. The max
// machinery is LOAD-BEARING (r4/r7/r8/r9 all failed without it). V must stay
// LDS-staged via global_load_lds (r12: direct V loads serialize the vmcnt
// pipeline, -77%). Do not touch.
__global__ __launch_bounds__(256, 4) void attn_kernel(const u16* __restrict__ Qp,
                                                      const u16* __restrict__ Kp,
                                                      const u16* __restrict__ Vp,
                                                      u16* __restrict__ Op) {
  const int tid = threadIdx.x;
  const int lane = tid & 63;
  const int wid = tid >> 6;

  // XCD-chunked mapping: xcd = id&7 owns heads [xcd*4, xcd*4+4)
  const int id = blockIdx.x;
  const int local = id >> 3;
  const int hb = (id & 7) * 4 + (local >> 5);   // 0..31 = b*16+h
  const int qt = local & 31;                    // 0..31
  const int b = hb >> 4;
  const int h = hb & 15;

  const u16* Qh = Qp + (size_t)hb * (2048 * 64);
  const u16* Kh = Kp + (size_t)hb * (2048 * 64);
  const u16* Vh = Vp + (size_t)hb * (64 * 2048);

  __shared__ __align__(16) u16 Kls[2][64 * 64];
  __shared__ __align__(16) u16 Vls[2][64 * 64];   // V^T tile: [d (64)][kk (64)]
  __shared__ __align__(16) u16 Pls[4][16 * 64];

  const int qrow0 = qt * 64 + wid * 16;
  const int lg = lane >> 4;       // 16-lane group 0..3
  const int lc = lane & 15;

  bf16x8 aq[2];
#pragma unroll
  for (int ks = 0; ks < 2; ++ks)
    aq[ks] = *(const bf16x8*)(Qh + (size_t)(qrow0 + lc) * 64 + ks * 32 + (lg << 3));

  // ---- loop-invariant LDS offsets ----
  int roff[4][2];     // K/V fragment read offsets (krow/drow formulas identical)
  int paoff[2];       // P A-fragment read offsets
  int pstoff[4][4];   // P store offsets
#pragma unroll
  for (int n = 0; n < 4; ++n)
#pragma unroll
    for (int ks = 0; ks < 2; ++ks)
      roff[n][ks] = swz128(n * 16 + lc, ks * 4 + lg);
#pragma unroll
  for (int ks = 0; ks < 2; ++ks) paoff[ks] = swz128(lc, ks * 4 + lg);
#pragma unroll
  for (int r = 0; r < 4; ++r) {
    const int prow = lg * 4 + r;
    const int swzr = (prow & 7) << 3;
#pragma unroll
    for (int j = 0; j < 4; ++j)
      pstoff[r][j] = prow * 64 + ((j * 16 + lc) ^ swzr);
  }

  // ---- loop-invariant staging pointers / LDS destinations ----
  const u16* kptr[2];
  const u16* vptr[2];
  int ldst[2];
#pragma unroll
  for (int i = 0; i < 2; ++i) {
    const int L = i * 256 + tid;
    const int r = L >> 3;
    const int c8 = (L & 7) ^ (r & 7);
    kptr[i] = Kh + r * 64 + c8 * 8;                 // + kt*4096 per tile
    vptr[i] = Vh + (size_t)r * 2048 + c8 * 8;       // + kt*64 per tile
    ldst[i] = L * 8;
  }

  float mrun[4], psum[4];
  f32x4 oacc[4] = {};
#pragma unroll
  for (int r = 0; r < 4; ++r) { mrun[r] = -__builtin_inff(); psum[r] = 0.f; }

  auto stage = [&](int kt, int buf) {
#pragma unroll
    for (int i = 0; i < 2; ++i) {
      gload16(kptr[i] + kt * 4096, &Kls[buf][ldst[i]]);
      gload16(vptr[i] + kt * 64, &Vls[buf][ldst[i]]);
    }
  };

  auto compute = [&](int buf) {
    // S = Q K^T  (16 q-rows x 64 keys per wave), scores in log2 units
    f32x4 s[4];
    __builtin_amdgcn_s_setprio(1);
#pragma unroll
    for (int n = 0; n < 4; ++n) {
      f32x4 sa = {0.f, 0.f, 0.f, 0.f};
#pragma unroll
      for (int ks = 0; ks < 2; ++ks) {
        bf16x8 kb = *(const bf16x8*)&Kls[buf][roff[n][ks]];
        sa = MFMA16(aq[ks], kb, sa);
      }
      s[n] = sa;
    }
    __builtin_amdgcn_s_setprio(0);

    // per-row tile max via DPP (rows live in 16-lane groups; reg r -> row lg*4+r)
    float t[4];
#pragma unroll
    for (int r = 0; r < 4; ++r)
      t[r] = rowmax16(fmaxf(fmaxf(fmaxf(s[0][r], s[1][r]), s[2][r]), s[3][r]));

    // defer-max: only rescale when some row grew by > 8 (log2 units; P <= 256)
    const bool small = (t[0] <= mrun[0] + 8.f) && (t[1] <= mrun[1] + 8.f) &&
                       (t[2] <= mrun[2] + 8.f) && (t[3] <= mrun[3] + 8.f);
    if (!__all((int)small)) {
#pragma unroll
      for (int r = 0; r < 4; ++r) {
        const float mnew = fmaxf(mrun[r], t[r]);
        const float fac = __builtin_amdgcn_exp2f(mrun[r] - mnew);
        mrun[r] = mnew;
        psum[r] *= fac;
#pragma unroll
        for (int n = 0; n < 4; ++n) oacc[n][r] *= fac;
      }
    }

    // exp2 + per-lane partial sum + pack P -> bf16 -> per-wave swizzled LDS
    u16* base = Pls[wid];
#pragma unroll
    for (int r = 0; r < 4; ++r) {
      const float m = mrun[r];
      const float e0 = __builtin_amdgcn_exp2f(s[0][r] - m);
      const float e1 = __builtin_amdgcn_exp2f(s[1][r] - m);
      const float e2 = __builtin_amdgcn_exp2f(s[2][r] - m);
      const float e3 = __builtin_amdgcn_exp2f(s[3][r] - m);
      psum[r] += (e0 + e1) + (e2 + e3);

      const unsigned pk0 = cvt_pk_bf16(e0, e1);   // cols lc, lc+16
      const unsigned pk1 = cvt_pk_bf16(e2, e3);   // cols lc+32, lc+48
      base[pstoff[r][0]] = (u16)pk0;
      base[pstoff[r][1]] = (u16)(pk0 >> 16);
      base[pstoff[r][2]] = (u16)pk1;
      base[pstoff[r][3]] = (u16)(pk1 >> 16);
    }

    // O += P V
    bf16x8 pa[2];
#pragma unroll
    for (int ks = 0; ks < 2; ++ks)
      pa[ks] = *(const bf16x8*)&Pls[wid][paoff[ks]];
    __builtin_amdgcn_s_setprio(1);
#pragma unroll
    for (int n = 0; n < 4; ++n) {
#pragma unroll
      for (int ks = 0; ks < 2; ++ks) {
        bf16x8 vb = *(const bf16x8*)&Vls[buf][roff[n][ks]];
        oacc[n] = MFMA16(pa[ks], vb, oacc[n]);
      }
    }
    __builtin_amdgcn_s_setprio(0);
  };

  stage(0, 0);
  __syncthreads();   // drain prologue staging

  for (int kt = 0; kt < 32; kt += 2) {
    stage(kt + 1, 1);            // kt+1 <= 31 always
    compute(0);
    __syncthreads();             // drains prefetch vmcnt + syncs buffers
    if (kt + 2 < 32) stage(kt + 2, 0);
    compute(1);
    __syncthreads();
  }

  // epilogue: one cross-lane reduce per row, normalize, store [B,S,H] bf16
  float inv[4];
#pragma unroll
  for (int r = 0; r < 4; ++r) inv[r] = 1.0f / rowsum16(psum[r]);
#pragma unroll
  for (int n = 0; n < 4; ++n) {
    const int d = n * 16 + lc;
#pragma unroll
    for (int r = 0; r < 4; ++r) {
      const int row = qrow0 + (lg << 2) + r;
      const float val = oacc[n][r] * inv[r];
      Op[((size_t)b * 2048 + row) * 1024 + h * 64 + d] = bf16u(val);
    }
  }
}

// ---------- launch ----------
extern "C" void kernel_launch(void* const* d_in, const int* in_sizes, int n_in,
                              void* d_out, int out_size, void* d_ws, size_t ws_size,
                              hipStream_t stream) {
  const float* q  = (const float*)d_in[0];
  const float* k  = (const float*)d_in[1];
  const float* v  = (const float*)d_in[2];
  const float* Wq = (const float*)d_in[3];
  const float* bq = (const float*)d_in[4];
  const float* Wk = (const float*)d_in[5];
  const float* bk = (const float*)d_in[6];
  const float* Wv = (const float*)d_in[7];
  const float* bv = (const float*)d_in[8];
  const float* Wo = (const float*)d_in[9];
  const float* bo = (const float*)d_in[10];

  u16* ws = (u16*)d_ws;
  const size_t NX = 4194304;  // B*S*H
  const size_t NW = 1048576;  // H*H
  u16* xq  = ws;
  u16* xk  = xq + NX;
  u16* xv  = xk + NX;
  u16* wqb = xv + NX;
  u16* wkb = wqb + NW;
  u16* wvb = wkb + NW;
  u16* wob = wvb + NW;
  u16* Qp  = wob + NW;
  u16* Kp  = Qp + NX;
  u16* Vp  = Kp + NX;
  u16* Ao  = Vp + NX;          // total 32M u16 = 64 MB

  cvt_all<<<16384, 256, 0, stream>>>(q, k, v, Wq, Wk, Wv, Wo,
                                     xq, xk, xv, wqb, wkb, wvb, wob);

  mha_gemm<0><<<dim3(64, 8, 3), 256, 0, stream>>>(xq, xk, xv, wqb, wkb, wvb,
                                                  bq, bk, bv, Qp, Kp, Vp, nullptr);

  attn_kernel<<<1024, 256, 0, stream>>>(Qp, Kp, Vp, Ao);

  mha_gemm<1><<<dim3(128, 8, 1), 256, 0, stream>>>(Ao, nullptr, nullptr, wob, nullptr, nullptr,
                                                   bo, nullptr, nullptr, nullptr, nullptr, nullptr,
                                                   (float*)d_out);
}

// Round 15
// 140.883 us; speedup vs baseline: 1.0115x; 1.0115x over previous
//
#include <hip/hip_runtime.h>
#include <hip/hip_bf16.h>
#include <cstdint>
#include <cstddef>

typedef unsigned short u16;
typedef __attribute__((ext_vector_type(8))) short bf16x8;
typedef __attribute__((ext_vector_type(4))) float f32x4;

#define MFMA16(a, b, c) __builtin_amdgcn_mfma_f32_16x16x32_bf16((a), (b), (c), 0, 0, 0)

// ---------- helpers ----------
__device__ __forceinline__ u16 bf16u(float f) {
  union { float f; unsigned u; } x; x.f = f;
  unsigned lsb = (x.u >> 16) & 1u;
  return (u16)((x.u + 0x7fffu + lsb) >> 16);   // RNE
}

__device__ __forceinline__ unsigned cvt_pk_bf16(float lo, float hi) {
  unsigned r;
  asm("v_cvt_pk_bf16_f32 %0, %1, %2" : "=v"(r) : "v"(lo), "v"(hi));
  return r;
}

// DPP rotate within 16-lane rows (VALU cross-lane reduce)
template <int N>
__device__ __forceinline__ float dpp_ror(float v) {
  int r = __builtin_amdgcn_update_dpp(0, __builtin_bit_cast(int, v),
                                      0x120 | N, 0xF, 0xF, false);
  return __builtin_bit_cast(float, r);
}
__device__ __forceinline__ float rowmax16(float v) {
  v = fmaxf(v, dpp_ror<1>(v));
  v = fmaxf(v, dpp_ror<2>(v));
  v = fmaxf(v, dpp_ror<4>(v));
  v = fmaxf(v, dpp_ror<8>(v));
  return v;
}
__device__ __forceinline__ float rowsum16(float v) {
  v += dpp_ror<1>(v);
  v += dpp_ror<2>(v);
  v += dpp_ror<4>(v);
  v += dpp_ror<8>(v);
  return v;
}

__device__ __forceinline__ void gload16(const void* g, void* l) {
  __builtin_amdgcn_global_load_lds(
      (const __attribute__((address_space(1))) unsigned int*)g,
      (__attribute__((address_space(3))) unsigned int*)l, 16, 0, 0);
}

// XOR-swizzled element offset for [rows][64] bf16 LDS tiles (128B rows, 8x16B units).
__device__ __forceinline__ int swz128(int row, int u) {
  return row * 64 + ((u ^ (row & 7)) << 3);
}

// ---------- fp32 -> bf16 convert (all 7 tensors, one launch, exact 1-D grid) ----------
// blocks 0..12287: q/k/v (4096 each); 12288..16383: Wq/Wk/Wv/Wo (1024 each)
__global__ __launch_bounds__(256) void cvt_all(
    const float* __restrict__ q, const float* __restrict__ k, const float* __restrict__ v,
    const float* __restrict__ wq, const float* __restrict__ wk,
    const float* __restrict__ wv, const float* __restrict__ wo,
    u16* __restrict__ xq, u16* __restrict__ xk, u16* __restrict__ xv,
    u16* __restrict__ wqb, u16* __restrict__ wkb, u16* __restrict__ wvb,
    u16* __restrict__ wob) {
  const int bid = blockIdx.x;
  const float* s;
  u16* d;
  int local;
  if (bid < 12288) {
    const int z = bid >> 12;          // 0..2
    local = bid & 4095;
    s = (z == 0) ? q : (z == 1 ? k : v);
    d = (z == 0) ? xq : (z == 1 ? xk : xv);
  } else {
    const int z = (bid - 12288) >> 10;   // 0..3
    local = (bid - 12288) & 1023;
    s = (z == 0) ? wq : (z == 1 ? wk : (z == 2 ? wv : wo));
    d = (z == 0) ? wqb : (z == 1 ? wkb : (z == 2 ? wvb : wob));
  }
  const int i = (local * 256 + threadIdx.x) * 4;
  float4 f = *(const float4*)(s + i);
  ushort4 o = make_ushort4(bf16u(f.x), bf16u(f.y), bf16u(f.z), bf16u(f.w));
  *(ushort4*)(d + i) = o;
}

// ---------- GEMM: C = A(bf16,[4096x1024]) * W^T(bf16,[1024x1024] row-major [N,K]) + bias ----------
// 64x128 tile: 6 blocks/CU capacity for QKV, 2 for out-proj. r14 tested 32x128
// for out-proj (4 blocks/CU): neutral — occupancy gain cancels staging-density
// loss. 64x128 is the measured optimum for both MODEs.
template <int MODE>
__global__ __launch_bounds__(256) void mha_gemm(
    const u16* __restrict__ A0, const u16* __restrict__ A1, const u16* __restrict__ A2,
    const u16* __restrict__ W0, const u16* __restrict__ W1, const u16* __restrict__ W2,
    const float* __restrict__ b0, const float* __restrict__ b1, const float* __restrict__ b2,
    u16* __restrict__ o0, u16* __restrict__ o1, u16* __restrict__ o2,
    float* __restrict__ of) {
  const int tid = threadIdx.x;
  const int lane = tid & 63;
  const int wid = tid >> 6;
  const int wr = wid >> 1, wc = wid & 1;   // wave tile: rows wr*32 (+2x16), cols wc*64 (+4x16)
  const int bm = blockIdx.x, bn = blockIdx.y;
  const int z = (MODE == 0) ? blockIdx.z : 0;

  const u16* Ap = (z == 0) ? A0 : (z == 1 ? A1 : A2);
  const u16* Wp = (z == 0) ? W0 : (z == 1 ? W1 : W2);
  const float* bias = (z == 0) ? b0 : (z == 1 ? b1 : b2);
  u16* ob = (z == 0) ? o0 : (z == 1 ? o1 : o2);

  __shared__ __align__(16) u16 Als[64 * 64];    // 8 KB
  __shared__ __align__(16) u16 Bls[128 * 64];   // 16 KB

  const u16* Abase = Ap + (size_t)bm * 64 * 1024;
  const u16* Wbase = Wp + (size_t)bn * 128 * 1024;

  // loop-invariant LDS read offsets
  int aoff[2][2], boff[2][4];
#pragma unroll
  for (int ks = 0; ks < 2; ++ks) {
#pragma unroll
    for (int m = 0; m < 2; ++m)
      aoff[ks][m] = swz128(wr * 32 + m * 16 + (lane & 15), ks * 4 + (lane >> 4));
#pragma unroll
    for (int n = 0; n < 4; ++n)
      boff[ks][n] = swz128(wc * 64 + n * 16 + (lane & 15), ks * 4 + (lane >> 4));
  }

  // loop-invariant staging pointers / LDS destinations
  const u16* aptr[2];   // A: 64 rows  -> 512 units  -> 2/thread
  const u16* wptr[4];   // B: 128 rows -> 1024 units -> 4/thread
  int lda[2], ldb[4];
#pragma unroll
  for (int i = 0; i < 4; ++i) {
    const int L = i * 256 + tid;
    const int r = L >> 3;
    const int c8 = (L & 7) ^ (r & 7);
    if (i < 2) {
      aptr[i] = Abase + (size_t)r * 1024 + c8 * 8;   // + kt*64 per tile
      lda[i] = L * 8;
    }
    wptr[i] = Wbase + (size_t)r * 1024 + c8 * 8;
    ldb[i] = L * 8;
  }

  f32x4 acc[2][4] = {};

  for (int kt = 0; kt < 16; ++kt) {
    const int k0 = kt * 64;
    __syncthreads();
#pragma unroll
    for (int i = 0; i < 2; ++i) gload16(aptr[i] + k0, &Als[lda[i]]);
#pragma unroll
    for (int i = 0; i < 4; ++i) gload16(wptr[i] + k0, &Bls[ldb[i]]);
    __syncthreads();
#pragma unroll
    for (int ks = 0; ks < 2; ++ks) {
      bf16x8 af[2], bw[4];
#pragma unroll
      for (int m = 0; m < 2; ++m) af[m] = *(const bf16x8*)&Als[aoff[ks][m]];
#pragma unroll
      for (int n = 0; n < 4; ++n) bw[n] = *(const bf16x8*)&Bls[boff[ks][n]];
#pragma unroll
      for (int m = 0; m < 2; ++m)
#pragma unroll
        for (int n = 0; n < 4; ++n)
          acc[m][n] = MFMA16(af[m], bw[n], acc[m][n]);
    }
  }

  // Q gets 1/sqrt(64) * log2(e) so attention scores are in exp2 domain
  const float scl = (MODE == 0 && z == 0) ? 0.125f * 1.4426950408889634f : 1.0f;
#pragma unroll
  for (int n = 0; n < 4; ++n) {
    const int col = bn * 128 + wc * 64 + n * 16 + (lane & 15);
    const float bb = bias[col];
#pragma unroll
    for (int m = 0; m < 2; ++m) {
#pragma unroll
      for (int r = 0; r < 4; ++r) {
        const int row = bm * 64 + wr * 32 + m * 16 + ((lane >> 4) << 2) + r;
        float val = acc[m][n][r] + bb;
        if (MODE == 0) {
          val *= scl;
          const int bi = row >> 11, ss = row & 2047;
          const int hh = col >> 6, dd = col & 63;
          size_t off;
          if (z == 2) off = (((size_t)(bi * 16 + hh)) * 64 + dd) * 2048 + ss;   // V^T
          else        off = (((size_t)(bi * 16 + hh)) * 2048 + ss) * 64 + dd;   // Q,K
          ob[off] = bf16u(val);
        } else {
          of[(size_t)row * 1024 + col] = val;
        }
      }
    }
  }
}

// ---------- flash attention (BYTE-IDENTICAL to r6/r10/r11/r13 — verified passing) ----------
// Q,K: [B,NH,S,64] bf16 (Q pre-scaled by 0.125*log2e => scores in log2 units).
// V: [B,NH,64,S] bf16 (transposed). Out: [B,S,H] bf16.
// Per-row running max + defer-max THR=8 + deferred denominator. The max
// machinery is LOAD-BEARING (r4/r7/r8/r9 all failed without it). V must stay
// LDS-staged via global_load_lds (r12: direct V loads serialize the vmcnt
// pipeline, -77%). Do not touch.
__global__ __launch_bounds__(256, 4) void attn_kernel(const u16* __restrict__ Qp,
                                                      const u16* __restrict__ Kp,
                                                      const u16* __restrict__ Vp,
                                                      u16* __restrict__ Op) {
  const int tid = threadIdx.x;
  const int lane = tid & 63;
  const int wid = tid >> 6;

  // XCD-chunked mapping: xcd = id&7 owns heads [xcd*4, xcd*4+4)
  const int id = blockIdx.x;
  const int local = id >> 3;
  const int hb = (id & 7) * 4 + (local >> 5);   // 0..31 = b*16+h
  const int qt = local & 31;                    // 0..31
  const int b = hb >> 4;
  const int h = hb & 15;

  const u16* Qh = Qp + (size_t)hb * (2048 * 64);
  const u16* Kh = Kp + (size_t)hb * (2048 * 64);
  const u16* Vh = Vp + (size_t)hb * (64 * 2048);

  __shared__ __align__(16) u16 Kls[2][64 * 64];
  __shared__ __align__(16) u16 Vls[2][64 * 64];   // V^T tile: [d (64)][kk (64)]
  __shared__ __align__(16) u16 Pls[4][16 * 64];

  const int qrow0 = qt * 64 + wid * 16;
  const int lg = lane >> 4;       // 16-lane group 0..3
  const int lc = lane & 15;

  bf16x8 aq[2];
#pragma unroll
  for (int ks = 0; ks < 2; ++ks)
    aq[ks] = *(const bf16x8*)(Qh + (size_t)(qrow0 + lc) * 64 + ks * 32 + (lg << 3));

  // ---- loop-invariant LDS offsets ----
  int roff[4][2];     // K/V fragment read offsets (krow/drow formulas identical)
  int paoff[2];       // P A-fragment read offsets
  int pstoff[4][4];   // P store offsets
#pragma unroll
  for (int n = 0; n < 4; ++n)
#pragma unroll
    for (int ks = 0; ks < 2; ++ks)
      roff[n][ks] = swz128(n * 16 + lc, ks * 4 + lg);
#pragma unroll
  for (int ks = 0; ks < 2; ++ks) paoff[ks] = swz128(lc, ks * 4 + lg);
#pragma unroll
  for (int r = 0; r < 4; ++r) {
    const int prow = lg * 4 + r;
    const int swzr = (prow & 7) << 3;
#pragma unroll
    for (int j = 0; j < 4; ++j)
      pstoff[r][j] = prow * 64 + ((j * 16 + lc) ^ swzr);
  }

  // ---- loop-invariant staging pointers / LDS destinations ----
  const u16* kptr[2];
  const u16* vptr[2];
  int ldst[2];
#pragma unroll
  for (int i = 0; i < 2; ++i) {
    const int L = i * 256 + tid;
    const int r = L >> 3;
    const int c8 = (L & 7) ^ (r & 7);
    kptr[i] = Kh + r * 64 + c8 * 8;                 // + kt*4096 per tile
    vptr[i] = Vh + (size_t)r * 2048 + c8 * 8;       // + kt*64 per tile
    ldst[i] = L * 8;
  }

  float mrun[4], psum[4];
  f32x4 oacc[4] = {};
#pragma unroll
  for (int r = 0; r < 4; ++r) { mrun[r] = -__builtin_inff(); psum[r] = 0.f; }

  auto stage = [&](int kt, int buf) {
#pragma unroll
    for (int i = 0; i < 2; ++i) {
      gload16(kptr[i] + kt * 4096, &Kls[buf][ldst[i]]);
      gload16(vptr[i] + kt * 64, &Vls[buf][ldst[i]]);
    }
  };

  auto compute = [&](int buf) {
    // S = Q K^T  (16 q-rows x 64 keys per wave), scores in log2 units
    f32x4 s[4];
    __builtin_amdgcn_s_setprio(1);
#pragma unroll
    for (int n = 0; n < 4; ++n) {
      f32x4 sa = {0.f, 0.f, 0.f, 0.f};
#pragma unroll
      for (int ks = 0; ks < 2; ++ks) {
        bf16x8 kb = *(const bf16x8*)&Kls[buf][roff[n][ks]];
        sa = MFMA16(aq[ks], kb, sa);
      }
      s[n] = sa;
    }
    __builtin_amdgcn_s_setprio(0);

    // per-row tile max via DPP (rows live in 16-lane groups; reg r -> row lg*4+r)
    float t[4];
#pragma unroll
    for (int r = 0; r < 4; ++r)
      t[r] = rowmax16(fmaxf(fmaxf(fmaxf(s[0][r], s[1][r]), s[2][r]), s[3][r]));

    // defer-max: only rescale when some row grew by > 8 (log2 units; P <= 256)
    const bool small = (t[0] <= mrun[0] + 8.f) && (t[1] <= mrun[1] + 8.f) &&
                       (t[2] <= mrun[2] + 8.f) && (t[3] <= mrun[3] + 8.f);
    if (!__all((int)small)) {
#pragma unroll
      for (int r = 0; r < 4; ++r) {
        const float mnew = fmaxf(mrun[r], t[r]);
        const float fac = __builtin_amdgcn_exp2f(mrun[r] - mnew);
        mrun[r] = mnew;
        psum[r] *= fac;
#pragma unroll
        for (int n = 0; n < 4; ++n) oacc[n][r] *= fac;
      }
    }

    // exp2 + per-lane partial sum + pack P -> bf16 -> per-wave swizzled LDS
    u16* base = Pls[wid];
#pragma unroll
    for (int r = 0; r < 4; ++r) {
      const float m = mrun[r];
      const float e0 = __builtin_amdgcn_exp2f(s[0][r] - m);
      const float e1 = __builtin_amdgcn_exp2f(s[1][r] - m);
      const float e2 = __builtin_amdgcn_exp2f(s[2][r] - m);
      const float e3 = __builtin_amdgcn_exp2f(s[3][r] - m);
      psum[r] += (e0 + e1) + (e2 + e3);

      const unsigned pk0 = cvt_pk_bf16(e0, e1);   // cols lc, lc+16
      const unsigned pk1 = cvt_pk_bf16(e2, e3);   // cols lc+32, lc+48
      base[pstoff[r][0]] = (u16)pk0;
      base[pstoff[r][1]] = (u16)(pk0 >> 16);
      base[pstoff[r][2]] = (u16)pk1;
      base[pstoff[r][3]] = (u16)(pk1 >> 16);
    }

    // O += P V
    bf16x8 pa[2];
#pragma unroll
    for (int ks = 0; ks < 2; ++ks)
      pa[ks] = *(const bf16x8*)&Pls[wid][paoff[ks]];
    __builtin_amdgcn_s_setprio(1);
#pragma unroll
    for (int n = 0; n < 4; ++n) {
#pragma unroll
      for (int ks = 0; ks < 2; ++ks) {
        bf16x8 vb = *(const bf16x8*)&Vls[buf][roff[n][ks]];
        oacc[n] = MFMA16(pa[ks], vb, oacc[n]);
      }
    }
    __builtin_amdgcn_s_setprio(0);
  };

  stage(0, 0);
  __syncthreads();   // drain prologue staging

  for (int kt = 0; kt < 32; kt += 2) {
    stage(kt + 1, 1);            // kt+1 <= 31 always
    compute(0);
    __syncthreads();             // drains prefetch vmcnt + syncs buffers
    if (kt + 2 < 32) stage(kt + 2, 0);
    compute(1);
    __syncthreads();
  }

  // epilogue: one cross-lane reduce per row, normalize, store [B,S,H] bf16
  float inv[4];
#pragma unroll
  for (int r = 0; r < 4; ++r) inv[r] = 1.0f / rowsum16(psum[r]);
#pragma unroll
  for (int n = 0; n < 4; ++n) {
    const int d = n * 16 + lc;
#pragma unroll
    for (int r = 0; r < 4; ++r) {
      const int row = qrow0 + (lg << 2) + r;
      const float val = oacc[n][r] * inv[r];
      Op[((size_t)b * 2048 + row) * 1024 + h * 64 + d] = bf16u(val);
    }
  }
}

// ---------- launch ----------
extern "C" void kernel_launch(void* const* d_in, const int* in_sizes, int n_in,
                              void* d_out, int out_size, void* d_ws, size_t ws_size,
                              hipStream_t stream) {
  const float* q  = (const float*)d_in[0];
  const float* k  = (const float*)d_in[1];
  const float* v  = (const float*)d_in[2];
  const float* Wq = (const float*)d_in[3];
  const float* bq = (const float*)d_in[4];
  const float* Wk = (const float*)d_in[5];
  const float* bk = (const float*)d_in[6];
  const float* Wv = (const float*)d_in[7];
  const float* bv = (const float*)d_in[8];
  const float* Wo = (const float*)d_in[9];
  const float* bo = (const float*)d_in[10];

  u16* ws = (u16*)d_ws;
  const size_t NX = 4194304;  // B*S*H
  const size_t NW = 1048576;  // H*H
  u16* xq  = ws;
  u16* xk  = xq + NX;
  u16* xv  = xk + NX;
  u16* wqb = xv + NX;
  u16* wkb = wqb + NW;
  u16* wvb = wkb + NW;
  u16* wob = wvb + NW;
  u16* Qp  = wob + NW;
  u16* Kp  = Qp + NX;
  u16* Vp  = Kp + NX;
  u16* Ao  = Vp + NX;          // total 32M u16 = 64 MB

  cvt_all<<<16384, 256, 0, stream>>>(q, k, v, Wq, Wk, Wv, Wo,
                                     xq, xk, xv, wqb, wkb, wvb, wob);

  mha_gemm<0><<<dim3(64, 8, 3), 256, 0, stream>>>(xq, xk, xv, wqb, wkb, wvb,
                                                  bq, bk, bv, Qp, Kp, Vp, nullptr);

  attn_kernel<<<1024, 256, 0, stream>>>(Qp, Kp, Vp, Ao);

  mha_gemm<1><<<dim3(64, 8, 1), 256, 0, stream>>>(Ao, nullptr, nullptr, wob, nullptr, nullptr,
                                                  bo, nullptr, nullptr, nullptr, nullptr, nullptr,
                                                  (float*)d_out);
}